// Round 4
// baseline (269.946 us; speedup 1.0000x reference)
//
#include <hip/hip_runtime.h>
#include <math.h>

// ---------------------------------------------------------------------------
// GCN 3-layer forward for MI355X — bf16 MFMA edition, XCD-partitioned scatter.
// CSR (dst-grouped) + per-edge norm built once, reused by all 3 layers.
// Dense transform = bf16 MFMA GEMM (16x16x32), fp32 accum, bf16 h.
// Aggregation = CSR gather SpMM over bf16 rows (256B/row), 16 gathers deep.
// Layer 3 fuses bias+relu+log_softmax (64 cols == 64 lanes).
// ---------------------------------------------------------------------------

typedef __attribute__((ext_vector_type(8))) short short8;
typedef __attribute__((ext_vector_type(4))) float f32x4;

__device__ inline unsigned short f2bf(float x) {
    unsigned int u = __float_as_uint(x);
    u += 0x7fffu + ((u >> 16) & 1u);   // round to nearest even
    return (unsigned short)(u >> 16);
}
__device__ inline float bf2f(unsigned short v) {
    return __uint_as_float((unsigned int)v << 16);
}

// ------------------------------- prep ---------------------------------------

__global__ void hist_kernel(const int* __restrict__ dst, int* __restrict__ counts, int E) {
    int e = blockIdx.x * blockDim.x + threadIdx.x;
    if (e < E) atomicAdd(&counts[dst[e]], 1);
}

__global__ void dinv_kernel(const int* __restrict__ counts, float* __restrict__ dinv, int N) {
    int v = blockIdx.x * blockDim.x + threadIdx.x;
    if (v < N) dinv[v] = rsqrtf((float)counts[v] + 1.0f);  // +1 self loop
}

__global__ __launch_bounds__(1024) void scan_phase1(const int* __restrict__ deg,
                                                    int* __restrict__ rowptr,
                                                    int* __restrict__ part, int n) {
    __shared__ int buf[1024];
    int tid = threadIdx.x;
    int i = blockIdx.x * 1024 + tid;
    int v = (i < n) ? deg[i] : 0;
    buf[tid] = v;
    __syncthreads();
    #pragma unroll
    for (int off = 1; off < 1024; off <<= 1) {
        int t = (tid >= off) ? buf[tid - off] : 0;
        __syncthreads();
        buf[tid] += t;
        __syncthreads();
    }
    if (i < n) rowptr[i] = buf[tid] - v;
    if (tid == 1023) part[blockIdx.x] = buf[1023];
}

__global__ __launch_bounds__(1024) void scan_phase2(int* __restrict__ part, int nchunks) {
    __shared__ int buf[1024];
    int tid = threadIdx.x;
    int v = (tid < nchunks) ? part[tid] : 0;
    buf[tid] = v;
    __syncthreads();
    #pragma unroll
    for (int off = 1; off < 1024; off <<= 1) {
        int t = (tid >= off) ? buf[tid - off] : 0;
        __syncthreads();
        buf[tid] += t;
        __syncthreads();
    }
    if (tid < nchunks) part[tid] = buf[tid] - v;
    if (tid == 1023) part[nchunks] = buf[1023];
}

__global__ void scan_phase3(int* __restrict__ rowptr, int* __restrict__ pos,
                            const int* __restrict__ part, int n, int nchunks) {
    int i = blockIdx.x * blockDim.x + threadIdx.x;
    if (i < n) {
        int r = rowptr[i] + part[i >> 10];
        rowptr[i] = r;
        pos[i] = r;
    } else if (i == n) {
        rowptr[n] = part[nchunks];
    }
}

// XCD-range-partitioned scatter: range = blockIdx % 8 (consecutive blocks
// round-robin across the 8 XCDs, so each dst range is written by ONE XCD ->
// epack lines fill completely in that XCD's L2 before writeback).
#define NPART 8
__global__ void scatter_part_kernel(const int* __restrict__ src, const int* __restrict__ dst,
                                    const float* __restrict__ dinv, int* __restrict__ pos,
                                    int2* __restrict__ ep, int E, int N, int nblk_per_part) {
    int part = blockIdx.x & (NPART - 1);
    int blk  = blockIdx.x / NPART;
    int npr = (N + NPART - 1) / NPART;
    int lo = part * npr;
    int hi = min(N, lo + npr);
    int stride = nblk_per_part * blockDim.x;
    for (int e = blk * blockDim.x + threadIdx.x; e < E; e += stride) {
        int d = dst[e];
        if (d >= lo && d < hi) {
            int s = src[e];
            int idx = atomicAdd(&pos[d], 1);
            ep[idx] = make_int2(s, __float_as_int(dinv[s] * dinv[d]));
        }
    }
}

__global__ void cast_bf16_kernel(const float* __restrict__ in, unsigned short* __restrict__ out,
                                 int n4) {  // n4 = n/4
    int i = blockIdx.x * blockDim.x + threadIdx.x;
    if (i < n4) {
        float4 v = *(const float4*)(in + (size_t)i * 4);
        ushort4 o;
        o.x = f2bf(v.x); o.y = f2bf(v.y); o.z = f2bf(v.z); o.w = f2bf(v.w);
        *(ushort4*)(out + (size_t)i * 4) = o;
    }
}

// Wt[n][k] = bf16(W[k][n]);  W is [K][H]
__global__ void transpose_cast_kernel(const float* __restrict__ W, unsigned short* __restrict__ Wt,
                                      int K, int H) {
    int i = blockIdx.x * blockDim.x + threadIdx.x;
    if (i < K * H) {
        int k = i / H, n = i - k * H;
        Wt[(size_t)n * K + k] = f2bf(W[i]);
    }
}

// ------------------------------ bf16 MFMA GEMM ------------------------------
// C[M][H] = A[M][128] @ W[128][H], A & Wt bf16, C bf16. Wt = W^T stored [H][128].
// BM=64, 256 threads (4 waves), wave owns a 16-row tile x all H cols.
template<int H>
__global__ __launch_bounds__(256) void gemm_mfma(const unsigned short* __restrict__ A,
                                                 const unsigned short* __restrict__ Wt,
                                                 unsigned short* __restrict__ C, int M) {
    __shared__ __attribute__((aligned(16))) unsigned short As[64][136];  // +8 pad
    __shared__ __attribute__((aligned(16))) unsigned short Ws[H][136];
    int tid = threadIdx.x;
    int row0 = blockIdx.x * 64;
    #pragma unroll
    for (int g = tid; g < 64 * 16; g += 256) {
        int r = g >> 4, c = g & 15;
        int gr = row0 + r;
        uint4 v = make_uint4(0, 0, 0, 0);
        if (gr < M) v = *(const uint4*)(A + (size_t)gr * 128 + c * 8);
        *(uint4*)&As[r][c * 8] = v;
    }
    #pragma unroll
    for (int g = tid; g < H * 16; g += 256) {
        int r = g >> 4, c = g & 15;
        *(uint4*)&Ws[r][c * 8] = *(const uint4*)(Wt + (size_t)r * 128 + c * 8);
    }
    __syncthreads();

    int wave = tid >> 6, lane = tid & 63;
    int lr = lane & 15;
    int lk = (lane >> 4) * 8;
    int rt = wave * 16;

    short8 af[4];
    #pragma unroll
    for (int ks = 0; ks < 4; ++ks)
        af[ks] = *(const short8*)&As[rt + lr][ks * 32 + lk];

    #pragma unroll
    for (int ct = 0; ct < H / 16; ++ct) {
        f32x4 acc = {0.f, 0.f, 0.f, 0.f};
        #pragma unroll
        for (int ks = 0; ks < 4; ++ks) {
            short8 wf = *(const short8*)&Ws[ct * 16 + lr][ks * 32 + lk];
            acc = __builtin_amdgcn_mfma_f32_16x16x32_bf16(af[ks], wf, acc, 0, 0, 0);
        }
        int gcol = ct * 16 + lr;
        #pragma unroll
        for (int r = 0; r < 4; ++r) {
            int grow = row0 + rt + (lane >> 4) * 4 + r;
            if (grow < M) C[(size_t)grow * H + gcol] = f2bf(acc[r]);
        }
    }
}

// ------------------------------- SpMM ---------------------------------------
// h is bf16 [N][128] viewed as uint [N][64]; one wave per node; 16 gathers deep.
__global__ __launch_bounds__(256) void spmm128_kernel(const unsigned int* __restrict__ h32,
                                                      const int* __restrict__ rowptr,
                                                      const int2* __restrict__ ep,
                                                      const float* __restrict__ dinv,
                                                      const float* __restrict__ bias,
                                                      unsigned int* __restrict__ out32, int N) {
    int wid = blockIdx.x * 4 + (threadIdx.x >> 6);
    int lane = threadIdx.x & 63;
    if (wid >= N) return;
    float dv = dinv[wid];
    float w = dv * dv;
    unsigned int hv = h32[(size_t)wid * 64 + lane];
    float ax = bf2f((unsigned short)(hv & 0xffff)) * w;
    float ay = bf2f((unsigned short)(hv >> 16)) * w;
    int beg = rowptr[wid], end = rowptr[wid + 1];
    int e = beg;
    for (; e + 16 <= end; e += 16) {
        int2 ed[16];
        unsigned int g[16];
        #pragma unroll
        for (int u = 0; u < 16; ++u) ed[u] = ep[e + u];
        #pragma unroll
        for (int u = 0; u < 16; ++u) g[u] = h32[(size_t)ed[u].x * 64 + lane];
        #pragma unroll
        for (int u = 0; u < 16; ++u) {
            float nm = __int_as_float(ed[u].y);
            ax += bf2f((unsigned short)(g[u] & 0xffff)) * nm;
            ay += bf2f((unsigned short)(g[u] >> 16)) * nm;
        }
    }
    if (e < end) {  // masked tail: dummy slots re-read edge e (L1 hit, norm=0)
        int cnt = end - e;
        int2 ed[16];
        unsigned int g[16];
        #pragma unroll
        for (int u = 0; u < 16; ++u) ed[u] = ep[(u < cnt) ? e + u : e];
        #pragma unroll
        for (int u = 0; u < 16; ++u) g[u] = h32[(size_t)ed[u].x * 64 + lane];
        #pragma unroll
        for (int u = 0; u < 16; ++u) {
            float nm = (u < cnt) ? __int_as_float(ed[u].y) : 0.0f;
            ax += bf2f((unsigned short)(g[u] & 0xffff)) * nm;
            ay += bf2f((unsigned short)(g[u] >> 16)) * nm;
        }
    }
    ax += bias[lane * 2];
    ay += bias[lane * 2 + 1];
    ax = fmaxf(ax, 0.0f);
    ay = fmaxf(ay, 0.0f);
    out32[(size_t)wid * 64 + lane] = (unsigned int)f2bf(ax) | ((unsigned int)f2bf(ay) << 16);
}

// Layer 3: h bf16 [N][64]; bias + relu + log_softmax across 64 lanes; fp32 out.
__global__ __launch_bounds__(256) void spmm64_lsm_kernel(const unsigned short* __restrict__ h16,
                                                         const int* __restrict__ rowptr,
                                                         const int2* __restrict__ ep,
                                                         const float* __restrict__ dinv,
                                                         const float* __restrict__ bias,
                                                         float* __restrict__ out, int N) {
    int wid = blockIdx.x * 4 + (threadIdx.x >> 6);
    int lane = threadIdx.x & 63;
    if (wid >= N) return;
    float dv = dinv[wid];
    float acc = bf2f(h16[(size_t)wid * 64 + lane]) * dv * dv;
    int beg = rowptr[wid], end = rowptr[wid + 1];
    int e = beg;
    for (; e + 16 <= end; e += 16) {
        int2 ed[16];
        unsigned short g[16];
        #pragma unroll
        for (int u = 0; u < 16; ++u) ed[u] = ep[e + u];
        #pragma unroll
        for (int u = 0; u < 16; ++u) g[u] = h16[(size_t)ed[u].x * 64 + lane];
        #pragma unroll
        for (int u = 0; u < 16; ++u) acc += bf2f(g[u]) * __int_as_float(ed[u].y);
    }
    if (e < end) {
        int cnt = end - e;
        int2 ed[16];
        unsigned short g[16];
        #pragma unroll
        for (int u = 0; u < 16; ++u) ed[u] = ep[(u < cnt) ? e + u : e];
        #pragma unroll
        for (int u = 0; u < 16; ++u) g[u] = h16[(size_t)ed[u].x * 64 + lane];
        #pragma unroll
        for (int u = 0; u < 16; ++u) {
            float nm = (u < cnt) ? __int_as_float(ed[u].y) : 0.0f;
            acc += bf2f(g[u]) * nm;
        }
    }
    acc += bias[lane];
    acc = fmaxf(acc, 0.0f);
    float m = acc;
    #pragma unroll
    for (int off = 32; off; off >>= 1) m = fmaxf(m, __shfl_xor(m, off));
    float ex = expf(acc - m);
    float ssum = ex;
    #pragma unroll
    for (int off = 32; off; off >>= 1) ssum += __shfl_xor(ssum, off);
    out[(size_t)wid * 64 + lane] = acc - m - logf(ssum);
}

// ------------------------------- launch -------------------------------------

extern "C" void kernel_launch(void* const* d_in, const int* in_sizes, int n_in,
                              void* d_out, int out_size, void* d_ws, size_t ws_size,
                              hipStream_t stream) {
    const float* x  = (const float*)d_in[0];
    const int*   ei = (const int*)d_in[1];
    const float* W1 = (const float*)d_in[2];
    const float* b1 = (const float*)d_in[3];
    const float* W2 = (const float*)d_in[4];
    const float* b2 = (const float*)d_in[5];
    const float* W3 = (const float*)d_in[6];
    const float* b3 = (const float*)d_in[7];
    float* out = (float*)d_out;

    const int IN = 128, HID = 128, OUT = 64;
    int N = in_sizes[0] / IN;
    int E = in_sizes[1] / 2;
    const int* srcp = ei;
    const int* dstp = ei + E;

    char* p = (char*)d_ws;
    auto alloc = [&](size_t bytes) {
        char* r = p;
        p += (bytes + 255) & ~(size_t)255;
        return r;
    };
    int*   deg    = (int*)alloc((size_t)N * 4);
    int*   rowptr = (int*)alloc((size_t)(N + 1) * 4);
    int*   pos    = (int*)alloc((size_t)N * 4);
    int*   part   = (int*)alloc((size_t)1025 * 4);
    int2*  epack  = (int2*)alloc((size_t)E * 8);
    float* dinv   = (float*)alloc((size_t)N * 4);
    unsigned short* xb   = (unsigned short*)alloc((size_t)N * IN * 2);
    unsigned short* W1t  = (unsigned short*)alloc((size_t)IN * HID * 2);
    unsigned short* W2t  = (unsigned short*)alloc((size_t)HID * HID * 2);
    unsigned short* W3t  = (unsigned short*)alloc((size_t)HID * OUT * 2);
    unsigned short* hbuf = (unsigned short*)alloc((size_t)N * HID * 2);
    unsigned short* abuf = (unsigned short*)alloc((size_t)N * HID * 2);

    // --- CSR build (once; shared by all 3 layers) ---
    hipMemsetAsync(deg, 0, (size_t)N * 4, stream);
    hist_kernel<<<(E + 255) / 256, 256, 0, stream>>>(dstp, deg, E);
    dinv_kernel<<<(N + 255) / 256, 256, 0, stream>>>(deg, dinv, N);
    int nchunks = (N + 1023) / 1024;
    scan_phase1<<<nchunks, 1024, 0, stream>>>(deg, rowptr, part, N);
    scan_phase2<<<1, 1024, 0, stream>>>(part, nchunks);
    scan_phase3<<<(N + 256) / 256, 256, 0, stream>>>(rowptr, pos, part, N, nchunks);
    int nblk_per_part = 512;
    scatter_part_kernel<<<NPART * nblk_per_part, 256, 0, stream>>>(srcp, dstp, dinv, pos,
                                                                   epack, E, N, nblk_per_part);

    // --- bf16 prep: cast x, transpose+cast weights ---
    cast_bf16_kernel<<<(N * IN / 4 + 255) / 256, 256, 0, stream>>>(x, xb, N * IN / 4);
    transpose_cast_kernel<<<(IN * HID + 255) / 256, 256, 0, stream>>>(W1, W1t, IN, HID);
    transpose_cast_kernel<<<(HID * HID + 255) / 256, 256, 0, stream>>>(W2, W2t, HID, HID);
    transpose_cast_kernel<<<(HID * OUT + 255) / 256, 256, 0, stream>>>(W3, W3t, HID, OUT);

    int nwave_blocks = (N + 3) / 4;
    int gemm_blocks = (N + 63) / 64;

    // --- layer 1 ---
    gemm_mfma<128><<<gemm_blocks, 256, 0, stream>>>(xb, W1t, hbuf, N);
    spmm128_kernel<<<nwave_blocks, 256, 0, stream>>>((const unsigned int*)hbuf, rowptr, epack,
                                                     dinv, b1, (unsigned int*)abuf, N);
    // --- layer 2 ---
    gemm_mfma<128><<<gemm_blocks, 256, 0, stream>>>(abuf, W2t, hbuf, N);
    spmm128_kernel<<<nwave_blocks, 256, 0, stream>>>((const unsigned int*)hbuf, rowptr, epack,
                                                     dinv, b2, (unsigned int*)abuf, N);
    // --- layer 3 (fused bias+relu+log_softmax) ---
    gemm_mfma<64><<<gemm_blocks, 256, 0, stream>>>(abuf, W3t, hbuf, N);
    spmm64_lsm_kernel<<<nwave_blocks, 256, 0, stream>>>(hbuf, rowptr, epack, dinv, b3, out, N);
}

// Round 5
// 239.727 us; speedup vs baseline: 1.1261x; 1.1261x over previous
//
#include <hip/hip_runtime.h>
#include <math.h>

// ---------------------------------------------------------------------------
// GCN 3-layer forward for MI355X — bf16 MFMA + dinv-premultiplied features.
// Identity used: agg[d] = dinv_d * ( sum_{s in N(d)} h'[s] + h'[d] ),
// where h' = dinv * (x @ W) is produced in the GEMM epilogue. This removes
// the per-edge norm entirely: edge stream is a bare col[] (4B), gather loop
// is pure add. CSR built once, reused by all 3 layers. Gather depth 8
// (depth 16 regressed: compiler serialized at VGPR=40).
// ---------------------------------------------------------------------------

typedef __attribute__((ext_vector_type(8))) short short8;
typedef __attribute__((ext_vector_type(4))) float f32x4;

__device__ inline unsigned short f2bf(float x) {
    unsigned int u = __float_as_uint(x);
    u += 0x7fffu + ((u >> 16) & 1u);   // round to nearest even
    return (unsigned short)(u >> 16);
}
__device__ inline float bf2f(unsigned short v) {
    return __uint_as_float((unsigned int)v << 16);
}

// ------------------------------- prep ---------------------------------------

__global__ void hist_kernel(const int* __restrict__ dst, int* __restrict__ counts, int E) {
    int e = blockIdx.x * blockDim.x + threadIdx.x;
    if (e < E) atomicAdd(&counts[dst[e]], 1);
}

__global__ void dinv_kernel(const int* __restrict__ counts, float* __restrict__ dinv, int N) {
    int v = blockIdx.x * blockDim.x + threadIdx.x;
    if (v < N) dinv[v] = rsqrtf((float)counts[v] + 1.0f);  // +1 self loop
}

__global__ __launch_bounds__(1024) void scan_phase1(const int* __restrict__ deg,
                                                    int* __restrict__ rowptr,
                                                    int* __restrict__ part, int n) {
    __shared__ int buf[1024];
    int tid = threadIdx.x;
    int i = blockIdx.x * 1024 + tid;
    int v = (i < n) ? deg[i] : 0;
    buf[tid] = v;
    __syncthreads();
    #pragma unroll
    for (int off = 1; off < 1024; off <<= 1) {
        int t = (tid >= off) ? buf[tid - off] : 0;
        __syncthreads();
        buf[tid] += t;
        __syncthreads();
    }
    if (i < n) rowptr[i] = buf[tid] - v;
    if (tid == 1023) part[blockIdx.x] = buf[1023];
}

__global__ __launch_bounds__(1024) void scan_phase2(int* __restrict__ part, int nchunks) {
    __shared__ int buf[1024];
    int tid = threadIdx.x;
    int v = (tid < nchunks) ? part[tid] : 0;
    buf[tid] = v;
    __syncthreads();
    #pragma unroll
    for (int off = 1; off < 1024; off <<= 1) {
        int t = (tid >= off) ? buf[tid - off] : 0;
        __syncthreads();
        buf[tid] += t;
        __syncthreads();
    }
    if (tid < nchunks) part[tid] = buf[tid] - v;
    if (tid == 1023) part[nchunks] = buf[1023];
}

__global__ void scan_phase3(int* __restrict__ rowptr, int* __restrict__ pos,
                            const int* __restrict__ part, int n, int nchunks) {
    int i = blockIdx.x * blockDim.x + threadIdx.x;
    if (i < n) {
        int r = rowptr[i] + part[i >> 10];
        rowptr[i] = r;
        pos[i] = r;
    } else if (i == n) {
        rowptr[n] = part[nchunks];
    }
}

// XCD-range-partitioned scatter: range = blockIdx % 8 keeps each dst range's
// col[] lines accumulating inside ONE XCD's L2. Payload is now only 4B/edge.
#define NPART 8
__global__ void scatter_part_kernel(const int* __restrict__ src, const int* __restrict__ dst,
                                    int* __restrict__ pos, int* __restrict__ col,
                                    int E, int N, int nblk_per_part) {
    int part = blockIdx.x & (NPART - 1);
    int blk  = blockIdx.x / NPART;
    int npr = (N + NPART - 1) / NPART;
    int lo = part * npr;
    int hi = min(N, lo + npr);
    int stride = nblk_per_part * blockDim.x;
    for (int e = blk * blockDim.x + threadIdx.x; e < E; e += stride) {
        int d = dst[e];
        if (d >= lo && d < hi) {
            int idx = atomicAdd(&pos[d], 1);
            col[idx] = src[e];
        }
    }
}

__global__ void cast_bf16_kernel(const float* __restrict__ in, unsigned short* __restrict__ out,
                                 int n4) {
    int i = blockIdx.x * blockDim.x + threadIdx.x;
    if (i < n4) {
        float4 v = *(const float4*)(in + (size_t)i * 4);
        ushort4 o;
        o.x = f2bf(v.x); o.y = f2bf(v.y); o.z = f2bf(v.z); o.w = f2bf(v.w);
        *(ushort4*)(out + (size_t)i * 4) = o;
    }
}

// Wt[n][k] = bf16(W[k][n]);  W is [K][H]
__global__ void transpose_cast_kernel(const float* __restrict__ W, unsigned short* __restrict__ Wt,
                                      int K, int H) {
    int i = blockIdx.x * blockDim.x + threadIdx.x;
    if (i < K * H) {
        int k = i / H, n = i - k * H;
        Wt[(size_t)n * K + k] = f2bf(W[i]);
    }
}

// ------------------------------ bf16 MFMA GEMM ------------------------------
// C[M][H] = dinv[row] * (A[M][128] @ W[128][H])   (dinv premultiplied epilogue)
// BM=64, 256 threads (4 waves), wave owns a 16-row tile x all H cols.
template<int H>
__global__ __launch_bounds__(256) void gemm_mfma(const unsigned short* __restrict__ A,
                                                 const unsigned short* __restrict__ Wt,
                                                 const float* __restrict__ dinv,
                                                 unsigned short* __restrict__ C, int M) {
    __shared__ __attribute__((aligned(16))) unsigned short As[64][136];  // +8 pad
    __shared__ __attribute__((aligned(16))) unsigned short Ws[H][136];
    int tid = threadIdx.x;
    int row0 = blockIdx.x * 64;
    #pragma unroll
    for (int g = tid; g < 64 * 16; g += 256) {
        int r = g >> 4, c = g & 15;
        int gr = row0 + r;
        uint4 v = make_uint4(0, 0, 0, 0);
        if (gr < M) v = *(const uint4*)(A + (size_t)gr * 128 + c * 8);
        *(uint4*)&As[r][c * 8] = v;
    }
    #pragma unroll
    for (int g = tid; g < H * 16; g += 256) {
        int r = g >> 4, c = g & 15;
        *(uint4*)&Ws[r][c * 8] = *(const uint4*)(Wt + (size_t)r * 128 + c * 8);
    }
    __syncthreads();

    int wave = tid >> 6, lane = tid & 63;
    int lr = lane & 15;
    int lk = (lane >> 4) * 8;
    int rt = wave * 16;

    short8 af[4];
    #pragma unroll
    for (int ks = 0; ks < 4; ++ks)
        af[ks] = *(const short8*)&As[rt + lr][ks * 32 + lk];

    float dv[4];
    #pragma unroll
    for (int r = 0; r < 4; ++r) {
        int grow = row0 + rt + (lane >> 4) * 4 + r;
        dv[r] = (grow < M) ? dinv[grow] : 0.0f;
    }

    #pragma unroll
    for (int ct = 0; ct < H / 16; ++ct) {
        f32x4 acc = {0.f, 0.f, 0.f, 0.f};
        #pragma unroll
        for (int ks = 0; ks < 4; ++ks) {
            short8 wf = *(const short8*)&Ws[ct * 16 + lr][ks * 32 + lk];
            acc = __builtin_amdgcn_mfma_f32_16x16x32_bf16(af[ks], wf, acc, 0, 0, 0);
        }
        int gcol = ct * 16 + lr;
        #pragma unroll
        for (int r = 0; r < 4; ++r) {
            int grow = row0 + rt + (lane >> 4) * 4 + r;
            if (grow < M) C[(size_t)grow * H + gcol] = f2bf(acc[r] * dv[r]);
        }
    }
}

// ------------------------------- SpMM ---------------------------------------
// h' is dinv-premultiplied bf16 [N][128] viewed as uint [N][64].
// out[d] = relu(dinv[d]*(sum of h'[s]) + bias); pure-add gather loop, depth 8.
__global__ __launch_bounds__(256) void spmm128_kernel(const unsigned int* __restrict__ h32,
                                                      const int* __restrict__ rowptr,
                                                      const int* __restrict__ col,
                                                      const float* __restrict__ dinv,
                                                      const float* __restrict__ bias,
                                                      unsigned int* __restrict__ out32, int N) {
    int wid = blockIdx.x * 4 + (threadIdx.x >> 6);
    int lane = threadIdx.x & 63;
    if (wid >= N) return;
    unsigned int hv = h32[(size_t)wid * 64 + lane];
    float ax = __uint_as_float(hv << 16);
    float ay = __uint_as_float(hv & 0xffff0000u);
    int beg = rowptr[wid], end = rowptr[wid + 1];
    int e = beg;
    for (; e + 8 <= end; e += 8) {
        int s[8];
        unsigned int g[8];
        #pragma unroll
        for (int u = 0; u < 8; ++u) s[u] = col[e + u];
        #pragma unroll
        for (int u = 0; u < 8; ++u) g[u] = h32[(size_t)s[u] * 64 + lane];
        #pragma unroll
        for (int u = 0; u < 8; ++u) {
            ax += __uint_as_float(g[u] << 16);
            ay += __uint_as_float(g[u] & 0xffff0000u);
        }
    }
    if (e < end) {
        int cnt = end - e;
        int s[8];
        unsigned int g[8];
        #pragma unroll
        for (int u = 0; u < 8; ++u) s[u] = col[(u < cnt) ? e + u : e];
        #pragma unroll
        for (int u = 0; u < 8; ++u) g[u] = h32[(size_t)s[u] * 64 + lane];
        #pragma unroll
        for (int u = 0; u < 8; ++u) {
            ax += (u < cnt) ? __uint_as_float(g[u] << 16) : 0.0f;
            ay += (u < cnt) ? __uint_as_float(g[u] & 0xffff0000u) : 0.0f;
        }
    }
    float dv = dinv[wid];
    ax = fmaxf(fmaf(ax, dv, bias[lane * 2]), 0.0f);
    ay = fmaxf(fmaf(ay, dv, bias[lane * 2 + 1]), 0.0f);
    out32[(size_t)wid * 64 + lane] = (unsigned int)f2bf(ax) | ((unsigned int)f2bf(ay) << 16);
}

// Layer 3: h' bf16 [N][64]; dinv scale + bias + relu + log_softmax; fp32 out.
__global__ __launch_bounds__(256) void spmm64_lsm_kernel(const unsigned short* __restrict__ h16,
                                                         const int* __restrict__ rowptr,
                                                         const int* __restrict__ col,
                                                         const float* __restrict__ dinv,
                                                         const float* __restrict__ bias,
                                                         float* __restrict__ out, int N) {
    int wid = blockIdx.x * 4 + (threadIdx.x >> 6);
    int lane = threadIdx.x & 63;
    if (wid >= N) return;
    float acc = bf2f(h16[(size_t)wid * 64 + lane]);
    int beg = rowptr[wid], end = rowptr[wid + 1];
    int e = beg;
    for (; e + 8 <= end; e += 8) {
        int s[8];
        unsigned short g[8];
        #pragma unroll
        for (int u = 0; u < 8; ++u) s[u] = col[e + u];
        #pragma unroll
        for (int u = 0; u < 8; ++u) g[u] = h16[(size_t)s[u] * 64 + lane];
        #pragma unroll
        for (int u = 0; u < 8; ++u) acc += bf2f(g[u]);
    }
    if (e < end) {
        int cnt = end - e;
        int s[8];
        unsigned short g[8];
        #pragma unroll
        for (int u = 0; u < 8; ++u) s[u] = col[(u < cnt) ? e + u : e];
        #pragma unroll
        for (int u = 0; u < 8; ++u) g[u] = h16[(size_t)s[u] * 64 + lane];
        #pragma unroll
        for (int u = 0; u < 8; ++u) acc += (u < cnt) ? bf2f(g[u]) : 0.0f;
    }
    acc = fmaxf(fmaf(acc, dinv[wid], bias[lane]), 0.0f);
    float m = acc;
    #pragma unroll
    for (int off = 32; off; off >>= 1) m = fmaxf(m, __shfl_xor(m, off));
    float ex = expf(acc - m);
    float ssum = ex;
    #pragma unroll
    for (int off = 32; off; off >>= 1) ssum += __shfl_xor(ssum, off);
    out[(size_t)wid * 64 + lane] = acc - m - logf(ssum);
}

// ------------------------------- launch -------------------------------------

extern "C" void kernel_launch(void* const* d_in, const int* in_sizes, int n_in,
                              void* d_out, int out_size, void* d_ws, size_t ws_size,
                              hipStream_t stream) {
    const float* x  = (const float*)d_in[0];
    const int*   ei = (const int*)d_in[1];
    const float* W1 = (const float*)d_in[2];
    const float* b1 = (const float*)d_in[3];
    const float* W2 = (const float*)d_in[4];
    const float* b2 = (const float*)d_in[5];
    const float* W3 = (const float*)d_in[6];
    const float* b3 = (const float*)d_in[7];
    float* out = (float*)d_out;

    const int IN = 128, HID = 128, OUT = 64;
    int N = in_sizes[0] / IN;
    int E = in_sizes[1] / 2;
    const int* srcp = ei;
    const int* dstp = ei + E;

    char* p = (char*)d_ws;
    auto alloc = [&](size_t bytes) {
        char* r = p;
        p += (bytes + 255) & ~(size_t)255;
        return r;
    };
    int*   deg    = (int*)alloc((size_t)N * 4);
    int*   rowptr = (int*)alloc((size_t)(N + 1) * 4);
    int*   pos    = (int*)alloc((size_t)N * 4);
    int*   part   = (int*)alloc((size_t)1025 * 4);
    int*   colv   = (int*)alloc((size_t)E * 4);
    float* dinv   = (float*)alloc((size_t)N * 4);
    unsigned short* xb   = (unsigned short*)alloc((size_t)N * IN * 2);
    unsigned short* W1t  = (unsigned short*)alloc((size_t)IN * HID * 2);
    unsigned short* W2t  = (unsigned short*)alloc((size_t)HID * HID * 2);
    unsigned short* W3t  = (unsigned short*)alloc((size_t)HID * OUT * 2);
    unsigned short* hbuf = (unsigned short*)alloc((size_t)N * HID * 2);
    unsigned short* abuf = (unsigned short*)alloc((size_t)N * HID * 2);

    // --- CSR build (once; shared by all 3 layers) ---
    hipMemsetAsync(deg, 0, (size_t)N * 4, stream);
    hist_kernel<<<(E + 255) / 256, 256, 0, stream>>>(dstp, deg, E);
    dinv_kernel<<<(N + 255) / 256, 256, 0, stream>>>(deg, dinv, N);
    int nchunks = (N + 1023) / 1024;
    scan_phase1<<<nchunks, 1024, 0, stream>>>(deg, rowptr, part, N);
    scan_phase2<<<1, 1024, 0, stream>>>(part, nchunks);
    scan_phase3<<<(N + 256) / 256, 256, 0, stream>>>(rowptr, pos, part, N, nchunks);
    int nblk_per_part = 512;
    scatter_part_kernel<<<NPART * nblk_per_part, 256, 0, stream>>>(srcp, dstp, pos, colv,
                                                                   E, N, nblk_per_part);

    // --- bf16 prep: cast x, transpose+cast weights ---
    cast_bf16_kernel<<<(N * IN / 4 + 255) / 256, 256, 0, stream>>>(x, xb, N * IN / 4);
    transpose_cast_kernel<<<(IN * HID + 255) / 256, 256, 0, stream>>>(W1, W1t, IN, HID);
    transpose_cast_kernel<<<(HID * HID + 255) / 256, 256, 0, stream>>>(W2, W2t, HID, HID);
    transpose_cast_kernel<<<(HID * OUT + 255) / 256, 256, 0, stream>>>(W3, W3t, HID, OUT);

    int nwave_blocks = (N + 3) / 4;
    int gemm_blocks = (N + 63) / 64;

    // --- layer 1 ---
    gemm_mfma<128><<<gemm_blocks, 256, 0, stream>>>(xb, W1t, dinv, hbuf, N);
    spmm128_kernel<<<nwave_blocks, 256, 0, stream>>>((const unsigned int*)hbuf, rowptr, colv,
                                                     dinv, b1, (unsigned int*)abuf, N);
    // --- layer 2 ---
    gemm_mfma<128><<<gemm_blocks, 256, 0, stream>>>(abuf, W2t, dinv, hbuf, N);
    spmm128_kernel<<<nwave_blocks, 256, 0, stream>>>((const unsigned int*)hbuf, rowptr, colv,
                                                     dinv, b2, (unsigned int*)abuf, N);
    // --- layer 3 (fused bias+relu+log_softmax) ---
    gemm_mfma<64><<<gemm_blocks, 256, 0, stream>>>(abuf, W3t, dinv, hbuf, N);
    spmm64_lsm_kernel<<<nwave_blocks, 256, 0, stream>>>(hbuf, rowptr, colv, dinv, b3, out, N);
}

// Round 6
// 228.659 us; speedup vs baseline: 1.1806x; 1.0484x over previous
//
#include <hip/hip_runtime.h>
#include <math.h>

// ---------------------------------------------------------------------------
// GCN 3-layer forward for MI355X — bf16 MFMA + dinv-premultiplied features +
// half-wave dual-edge-stream SpMM (2 rows in flight per load instruction).
// Identity: agg[d] = dinv_d * ( sum_{s in N(d)} h'[s] + h'[d] ),
// h' = dinv * (x @ W) produced in the GEMM epilogue -> edge stream is a bare
// col[] (4B/edge), gather loop is pure add. CSR built once for all 3 layers.
// ---------------------------------------------------------------------------

typedef __attribute__((ext_vector_type(8))) short short8;
typedef __attribute__((ext_vector_type(4))) float f32x4;

__device__ inline unsigned short f2bf(float x) {
    unsigned int u = __float_as_uint(x);
    u += 0x7fffu + ((u >> 16) & 1u);   // round to nearest even
    return (unsigned short)(u >> 16);
}
__device__ inline float bf2f(unsigned short v) {
    return __uint_as_float((unsigned int)v << 16);
}

// ------------------------------- prep ---------------------------------------

__global__ void hist_kernel(const int* __restrict__ dst, int* __restrict__ counts, int E) {
    int e = blockIdx.x * blockDim.x + threadIdx.x;
    if (e < E) atomicAdd(&counts[dst[e]], 1);
}

__global__ __launch_bounds__(1024) void scan_phase1(const int* __restrict__ deg,
                                                    int* __restrict__ rowptr,
                                                    int* __restrict__ part, int n) {
    __shared__ int buf[1024];
    int tid = threadIdx.x;
    int i = blockIdx.x * 1024 + tid;
    int v = (i < n) ? deg[i] : 0;
    buf[tid] = v;
    __syncthreads();
    #pragma unroll
    for (int off = 1; off < 1024; off <<= 1) {
        int t = (tid >= off) ? buf[tid - off] : 0;
        __syncthreads();
        buf[tid] += t;
        __syncthreads();
    }
    if (i < n) rowptr[i] = buf[tid] - v;
    if (tid == 1023) part[blockIdx.x] = buf[1023];
}

__global__ __launch_bounds__(1024) void scan_phase2(int* __restrict__ part, int nchunks) {
    __shared__ int buf[1024];
    int tid = threadIdx.x;
    int v = (tid < nchunks) ? part[tid] : 0;
    buf[tid] = v;
    __syncthreads();
    #pragma unroll
    for (int off = 1; off < 1024; off <<= 1) {
        int t = (tid >= off) ? buf[tid - off] : 0;
        __syncthreads();
        buf[tid] += t;
        __syncthreads();
    }
    if (tid < nchunks) part[tid] = buf[tid] - v;
    if (tid == 1023) part[nchunks] = buf[1023];
}

// finalize rowptr, init pos, compute dinv (folds old dinv_kernel)
__global__ void scan_phase3(int* __restrict__ rowptr, int* __restrict__ pos,
                            const int* __restrict__ part, const int* __restrict__ deg,
                            float* __restrict__ dinv, int n, int nchunks) {
    int i = blockIdx.x * blockDim.x + threadIdx.x;
    if (i < n) {
        int r = rowptr[i] + part[i >> 10];
        rowptr[i] = r;
        pos[i] = r;
        dinv[i] = rsqrtf((float)deg[i] + 1.0f);  // +1 self loop
    } else if (i == n) {
        rowptr[n] = part[nchunks];
    }
}

// XCD-range-partitioned scatter: range = blockIdx % 8 keeps each dst range's
// col[] lines accumulating inside ONE XCD's L2. Payload is 4B/edge.
#define NPART 8
__global__ void scatter_part_kernel(const int* __restrict__ src, const int* __restrict__ dst,
                                    int* __restrict__ pos, int* __restrict__ col,
                                    int E, int N, int nblk_per_part) {
    int part = blockIdx.x & (NPART - 1);
    int blk  = blockIdx.x / NPART;
    int npr = (N + NPART - 1) / NPART;
    int lo = part * npr;
    int hi = min(N, lo + npr);
    int stride = nblk_per_part * blockDim.x;
    for (int e = blk * blockDim.x + threadIdx.x; e < E; e += stride) {
        int d = dst[e];
        if (d >= lo && d < hi) {
            int idx = atomicAdd(&pos[d], 1);
            col[idx] = src[e];
        }
    }
}

// one kernel for all 3 weight transposes: Wt[n][k] = bf16(W[k][n])
__global__ void wprep_kernel(const float* __restrict__ W1, unsigned short* __restrict__ W1t,
                             const float* __restrict__ W2, unsigned short* __restrict__ W2t,
                             const float* __restrict__ W3, unsigned short* __restrict__ W3t) {
    int i = blockIdx.x * blockDim.x + threadIdx.x;
    // W1: 128x128, W2: 128x128, W3: 128x64
    if (i < 16384) {
        int k = i >> 7, n = i & 127;
        W1t[(size_t)n * 128 + k] = f2bf(W1[i]);
    } else if (i < 32768) {
        int j = i - 16384;
        int k = j >> 7, n = j & 127;
        W2t[(size_t)n * 128 + k] = f2bf(W2[j]);
    } else if (i < 40960) {
        int j = i - 32768;
        int k = j >> 6, n = j & 63;
        W3t[(size_t)n * 128 + k] = f2bf(W3[j]);
    }
}

// ------------------------------ bf16 MFMA GEMM ------------------------------
// C[M][H] = dinv[row] * (A[M][128] @ W[128][H]); A bf16 or fp32 (AF32 path
// casts during LDS staging -> no separate cast kernel for x).
template<int H, bool AF32>
__global__ __launch_bounds__(256) void gemm_mfma(const void* __restrict__ Av,
                                                 const unsigned short* __restrict__ Wt,
                                                 const float* __restrict__ dinv,
                                                 unsigned short* __restrict__ C, int M) {
    __shared__ __attribute__((aligned(16))) unsigned short As[64][136];  // +8 pad
    __shared__ __attribute__((aligned(16))) unsigned short Ws[H][136];
    int tid = threadIdx.x;
    int row0 = blockIdx.x * 64;
    if (AF32) {
        const float* A = (const float*)Av;
        #pragma unroll
        for (int g = tid; g < 64 * 32; g += 256) {
            int r = g >> 5, c = g & 31;   // c indexes float4 chunks (4 elems)
            int gr = row0 + r;
            ushort4 o = make_ushort4(0, 0, 0, 0);
            if (gr < M) {
                float4 v = *(const float4*)(A + (size_t)gr * 128 + c * 4);
                o.x = f2bf(v.x); o.y = f2bf(v.y); o.z = f2bf(v.z); o.w = f2bf(v.w);
            }
            *(ushort4*)&As[r][c * 4] = o;
        }
    } else {
        const unsigned short* A = (const unsigned short*)Av;
        #pragma unroll
        for (int g = tid; g < 64 * 16; g += 256) {
            int r = g >> 4, c = g & 15;
            int gr = row0 + r;
            uint4 v = make_uint4(0, 0, 0, 0);
            if (gr < M) v = *(const uint4*)(A + (size_t)gr * 128 + c * 8);
            *(uint4*)&As[r][c * 8] = v;
        }
    }
    #pragma unroll
    for (int g = tid; g < H * 16; g += 256) {
        int r = g >> 4, c = g & 15;
        *(uint4*)&Ws[r][c * 8] = *(const uint4*)(Wt + (size_t)r * 128 + c * 8);
    }
    __syncthreads();

    int wave = tid >> 6, lane = tid & 63;
    int lr = lane & 15;
    int lk = (lane >> 4) * 8;
    int rt = wave * 16;

    short8 af[4];
    #pragma unroll
    for (int ks = 0; ks < 4; ++ks)
        af[ks] = *(const short8*)&As[rt + lr][ks * 32 + lk];

    float dv[4];
    #pragma unroll
    for (int r = 0; r < 4; ++r) {
        int grow = row0 + rt + (lane >> 4) * 4 + r;
        dv[r] = (grow < M) ? dinv[grow] : 0.0f;
    }

    #pragma unroll
    for (int ct = 0; ct < H / 16; ++ct) {
        f32x4 acc = {0.f, 0.f, 0.f, 0.f};
        #pragma unroll
        for (int ks = 0; ks < 4; ++ks) {
            short8 wf = *(const short8*)&Ws[ct * 16 + lr][ks * 32 + lk];
            acc = __builtin_amdgcn_mfma_f32_16x16x32_bf16(af[ks], wf, acc, 0, 0, 0);
        }
        int gcol = ct * 16 + lr;
        #pragma unroll
        for (int r = 0; r < 4; ++r) {
            int grow = row0 + rt + (lane >> 4) * 4 + r;
            if (grow < M) C[(size_t)grow * H + gcol] = f2bf(acc[r] * dv[r]);
        }
    }
}

// ------------------------------- SpMM ---------------------------------------
// Half-wave dual-stream gather: lanes 0-31 process even edges, 32-63 odd edges.
// For HID=128 each half-lane loads uint2 (4 channels, 32 lanes = full 256B row).
// Depth 8 pairs -> 16 edges in flight per wave.
__global__ __launch_bounds__(256) void spmm128_kernel(const uint2* __restrict__ h2,
                                                      const int* __restrict__ rowptr,
                                                      const int* __restrict__ col,
                                                      const float* __restrict__ dinv,
                                                      const float* __restrict__ bias,
                                                      uint2* __restrict__ out2, int N) {
    int wid = blockIdx.x * 4 + (threadIdx.x >> 6);
    int lane = threadIdx.x & 63;
    if (wid >= N) return;
    int half = lane >> 5;        // which edge stream
    int c    = lane & 31;        // channel group: channels 4c..4c+3
    uint2 hv = h2[(size_t)wid * 32 + c];
    float a0 = __uint_as_float(hv.x << 16);
    float a1 = __uint_as_float(hv.x & 0xffff0000u);
    float a2 = __uint_as_float(hv.y << 16);
    float a3 = __uint_as_float(hv.y & 0xffff0000u);
    int beg = rowptr[wid], end = rowptr[wid + 1];
    int deg = end - beg;
    int q = 0;
    for (; 2 * (q + 8) <= deg; q += 8) {          // all 16 slots valid
        int s[8];
        uint2 g[8];
        #pragma unroll
        for (int u = 0; u < 8; ++u) s[u] = col[beg + 2 * (q + u) + half];
        #pragma unroll
        for (int u = 0; u < 8; ++u) g[u] = h2[(size_t)s[u] * 32 + c];
        #pragma unroll
        for (int u = 0; u < 8; ++u) {
            a0 += __uint_as_float(g[u].x << 16);
            a1 += __uint_as_float(g[u].x & 0xffff0000u);
            a2 += __uint_as_float(g[u].y << 16);
            a3 += __uint_as_float(g[u].y & 0xffff0000u);
        }
    }
    int P = (deg + 1) >> 1;                        // total pairs
    if (q < P) {                                   // tail: per-slot validity
        int s[8];
        uint2 g[8];
        bool vl[8];
        #pragma unroll
        for (int u = 0; u < 8; ++u) {
            int e = beg + 2 * (q + u) + half;
            vl[u] = e < end;
            s[u] = col[vl[u] ? e : beg];           // beg valid since deg>=1 here
        }
        #pragma unroll
        for (int u = 0; u < 8; ++u) g[u] = h2[(size_t)s[u] * 32 + c];
        #pragma unroll
        for (int u = 0; u < 8; ++u) {
            a0 += vl[u] ? __uint_as_float(g[u].x << 16) : 0.0f;
            a1 += vl[u] ? __uint_as_float(g[u].x & 0xffff0000u) : 0.0f;
            a2 += vl[u] ? __uint_as_float(g[u].y << 16) : 0.0f;
            a3 += vl[u] ? __uint_as_float(g[u].y & 0xffff0000u) : 0.0f;
        }
    }
    // combine the two edge streams
    a0 += __shfl_xor(a0, 32);
    a1 += __shfl_xor(a1, 32);
    a2 += __shfl_xor(a2, 32);
    a3 += __shfl_xor(a3, 32);
    float dv = dinv[wid];
    float4 b4 = ((const float4*)bias)[c];
    a0 = fmaxf(fmaf(a0, dv, b4.x), 0.0f);
    a1 = fmaxf(fmaf(a1, dv, b4.y), 0.0f);
    a2 = fmaxf(fmaf(a2, dv, b4.z), 0.0f);
    a3 = fmaxf(fmaf(a3, dv, b4.w), 0.0f);
    if (half == 0) {
        uint2 o;
        o.x = (unsigned int)f2bf(a0) | ((unsigned int)f2bf(a1) << 16);
        o.y = (unsigned int)f2bf(a2) | ((unsigned int)f2bf(a3) << 16);
        out2[(size_t)wid * 32 + c] = o;
    }
}

// Layer 3: OUT=64, h row = 128B = 32 lanes x uint (2 channels/lane).
// Same half-wave dual-stream structure + fused bias/relu/log_softmax.
__global__ __launch_bounds__(256) void spmm64_lsm_kernel(const unsigned int* __restrict__ h1,
                                                         const int* __restrict__ rowptr,
                                                         const int* __restrict__ col,
                                                         const float* __restrict__ dinv,
                                                         const float* __restrict__ bias,
                                                         float2* __restrict__ out2, int N) {
    int wid = blockIdx.x * 4 + (threadIdx.x >> 6);
    int lane = threadIdx.x & 63;
    if (wid >= N) return;
    int half = lane >> 5;
    int c    = lane & 31;        // channels 2c, 2c+1
    unsigned int hv = h1[(size_t)wid * 32 + c];
    float a0 = __uint_as_float(hv << 16);
    float a1 = __uint_as_float(hv & 0xffff0000u);
    int beg = rowptr[wid], end = rowptr[wid + 1];
    int deg = end - beg;
    int q = 0;
    for (; 2 * (q + 8) <= deg; q += 8) {
        int s[8];
        unsigned int g[8];
        #pragma unroll
        for (int u = 0; u < 8; ++u) s[u] = col[beg + 2 * (q + u) + half];
        #pragma unroll
        for (int u = 0; u < 8; ++u) g[u] = h1[(size_t)s[u] * 32 + c];
        #pragma unroll
        for (int u = 0; u < 8; ++u) {
            a0 += __uint_as_float(g[u] << 16);
            a1 += __uint_as_float(g[u] & 0xffff0000u);
        }
    }
    int P = (deg + 1) >> 1;
    if (q < P) {
        int s[8];
        unsigned int g[8];
        bool vl[8];
        #pragma unroll
        for (int u = 0; u < 8; ++u) {
            int e = beg + 2 * (q + u) + half;
            vl[u] = e < end;
            s[u] = col[vl[u] ? e : beg];
        }
        #pragma unroll
        for (int u = 0; u < 8; ++u) g[u] = h1[(size_t)s[u] * 32 + c];
        #pragma unroll
        for (int u = 0; u < 8; ++u) {
            a0 += vl[u] ? __uint_as_float(g[u] << 16) : 0.0f;
            a1 += vl[u] ? __uint_as_float(g[u] & 0xffff0000u) : 0.0f;
        }
    }
    a0 += __shfl_xor(a0, 32);
    a1 += __shfl_xor(a1, 32);
    float dv = dinv[wid];
    float2 b2 = ((const float2*)bias)[c];
    a0 = fmaxf(fmaf(a0, dv, b2.x), 0.0f);
    a1 = fmaxf(fmaf(a1, dv, b2.y), 0.0f);
    // log_softmax over 64 channels = 32 lanes x 2 regs (halves hold duplicates)
    float m = fmaxf(a0, a1);
    #pragma unroll
    for (int off = 16; off; off >>= 1) m = fmaxf(m, __shfl_xor(m, off));
    float ssum = expf(a0 - m) + expf(a1 - m);
    #pragma unroll
    for (int off = 16; off; off >>= 1) ssum += __shfl_xor(ssum, off);
    float lse = m + logf(ssum);
    if (half == 0) {
        float2 o;
        o.x = a0 - lse;
        o.y = a1 - lse;
        out2[(size_t)wid * 32 + c] = o;
    }
}

// ------------------------------- launch -------------------------------------

extern "C" void kernel_launch(void* const* d_in, const int* in_sizes, int n_in,
                              void* d_out, int out_size, void* d_ws, size_t ws_size,
                              hipStream_t stream) {
    const float* x  = (const float*)d_in[0];
    const int*   ei = (const int*)d_in[1];
    const float* W1 = (const float*)d_in[2];
    const float* b1 = (const float*)d_in[3];
    const float* W2 = (const float*)d_in[4];
    const float* b2 = (const float*)d_in[5];
    const float* W3 = (const float*)d_in[6];
    const float* b3 = (const float*)d_in[7];
    float* out = (float*)d_out;

    const int IN = 128, HID = 128, OUT = 64;
    int N = in_sizes[0] / IN;
    int E = in_sizes[1] / 2;
    const int* srcp = ei;
    const int* dstp = ei + E;

    char* p = (char*)d_ws;
    auto alloc = [&](size_t bytes) {
        char* r = p;
        p += (bytes + 255) & ~(size_t)255;
        return r;
    };
    int*   deg    = (int*)alloc((size_t)N * 4);
    int*   rowptr = (int*)alloc((size_t)(N + 1) * 4);
    int*   pos    = (int*)alloc((size_t)N * 4);
    int*   part   = (int*)alloc((size_t)1025 * 4);
    int*   colv   = (int*)alloc((size_t)E * 4);
    float* dinv   = (float*)alloc((size_t)N * 4);
    unsigned short* W1t  = (unsigned short*)alloc((size_t)IN * HID * 2);
    unsigned short* W2t  = (unsigned short*)alloc((size_t)HID * HID * 2);
    unsigned short* W3t  = (unsigned short*)alloc((size_t)HID * OUT * 2);
    unsigned short* hbuf = (unsigned short*)alloc((size_t)N * HID * 2);
    unsigned short* abuf = (unsigned short*)alloc((size_t)N * HID * 2);

    // --- CSR build (once; shared by all 3 layers) ---
    hipMemsetAsync(deg, 0, (size_t)N * 4, stream);
    hist_kernel<<<(E + 255) / 256, 256, 0, stream>>>(dstp, deg, E);
    int nchunks = (N + 1023) / 1024;
    scan_phase1<<<nchunks, 1024, 0, stream>>>(deg, rowptr, part, N);
    scan_phase2<<<1, 1024, 0, stream>>>(part, nchunks);
    scan_phase3<<<(N + 256) / 256, 256, 0, stream>>>(rowptr, pos, part, deg, dinv, N, nchunks);
    int nblk_per_part = 512;
    scatter_part_kernel<<<NPART * nblk_per_part, 256, 0, stream>>>(srcp, dstp, pos, colv,
                                                                   E, N, nblk_per_part);
    // weight transpose+cast (one kernel for all three)
    wprep_kernel<<<(40960 + 255) / 256, 256, 0, stream>>>(W1, W1t, W2, W2t, W3, W3t);

    int nwave_blocks = (N + 3) / 4;
    int gemm_blocks = (N + 63) / 64;

    // --- layer 1 (x fp32 cast in staging) ---
    gemm_mfma<128, true><<<gemm_blocks, 256, 0, stream>>>(x, W1t, dinv, hbuf, N);
    spmm128_kernel<<<nwave_blocks, 256, 0, stream>>>((const uint2*)hbuf, rowptr, colv,
                                                     dinv, b1, (uint2*)abuf, N);
    // --- layer 2 ---
    gemm_mfma<128, false><<<gemm_blocks, 256, 0, stream>>>(abuf, W2t, dinv, hbuf, N);
    spmm128_kernel<<<nwave_blocks, 256, 0, stream>>>((const uint2*)hbuf, rowptr, colv,
                                                     dinv, b2, (uint2*)abuf, N);
    // --- layer 3 (fused bias+relu+log_softmax) ---
    gemm_mfma<64, false><<<gemm_blocks, 256, 0, stream>>>(abuf, W3t, dinv, hbuf, N);
    spmm64_lsm_kernel<<<nwave_blocks, 256, 0, stream>>>((const unsigned int*)hbuf, rowptr, colv,
                                                        dinv, b3, (float2*)out, N);
}